// Round 13
// baseline (196.029 us; speedup 1.0000x reference)
//
#include <hip/hip_runtime.h>
#include <hip/hip_bf16.h>
#include <math.h>

#define EMBED_DIM 1024
#define NUM_HEADS 16
#define HEAD_DIM 64
#define BATCH 2
#define SEQ 2048

using short8  = __attribute__((ext_vector_type(8))) short;
using floatx4 = __attribute__((ext_vector_type(4))) float;

__device__ __forceinline__ ushort f2bf(float f) {
    unsigned u = __float_as_uint(f);
    u = (u + 0x7FFFu + ((u >> 16) & 1u)) >> 16;   // RNE
    return (ushort)u;
}

// pack two floats to bf16x2 (half-up rounding — P values are in [0,1], fine)
__device__ __forceinline__ unsigned bfpack2(float a, float b) {
    return ((__float_as_uint(a) + 0x8000u) >> 16) |
           (((__float_as_uint(b) + 0x8000u) >> 16) << 16);
}

// async global->LDS, 16B per lane; LDS dest = wave-uniform base + lane*16.
__device__ __forceinline__ void load_lds16(const ushort* g, ushort* l) {
    __builtin_amdgcn_global_load_lds(
        (const __attribute__((address_space(1))) void*)g,
        (__attribute__((address_space(3))) void*)l, 16, 0, 0);
}

// ---------------------------------------------------------------------------
// Fused prep: cast x -> bf16, transpose+cast W_qkv and W_out.
// ---------------------------------------------------------------------------
__device__ __forceinline__ void tc_tile(
    const float* __restrict__ W, ushort* __restrict__ Wt,
    int K, int N, int n0, int k0, float (*t)[65])
{
    const int c = threadIdx.x & 63, r0 = (threadIdx.x >> 6) * 16;
    #pragma unroll
    for (int r = 0; r < 16; ++r)
        t[r0 + r][c] = W[(size_t)(k0 + r0 + r) * N + n0 + c];
    __syncthreads();
    #pragma unroll
    for (int r = 0; r < 16; ++r)
        Wt[(size_t)(n0 + r0 + r) * K + k0 + c] = f2bf(t[c][r0 + r]);
}

__global__ __launch_bounds__(256) void prep_all(
    const float* __restrict__ x, const float* __restrict__ W_qkv,
    const float* __restrict__ W_out,
    ushort* __restrict__ xb, ushort* __restrict__ Wqb_t, ushort* __restrict__ Wob_t)
{
    __shared__ float t[64][65];
    const int bx = blockIdx.x;
    if (bx < 4096) {
        int i = (bx * 256 + threadIdx.x) * 4;
        float4 v = *(const float4*)&x[i];
        ushort4 o = { f2bf(v.x), f2bf(v.y), f2bf(v.z), f2bf(v.w) };
        *(ushort4*)&xb[i] = o;
    } else if (bx < 4096 + 768) {
        int b = bx - 4096;
        tc_tile(W_qkv, Wqb_t, 1024, 3072, (b % 48) * 64, (b / 48) * 64, t);
    } else {
        int b = bx - 4864;
        tc_tile(W_out, Wob_t, 1024, 1024, (b % 16) * 64, (b / 16) * 64, t);
    }
}

// ---------------------------------------------------------------------------
// bf16 MFMA GEMM core, 128x128, double-buffered — round-0 best (46.5us).
// Measured local optimum (rounds 1-6). Parked; used by gemm_qkv only.
// ---------------------------------------------------------------------------
#define GK 1024

__device__ __forceinline__ void gemm_core(
    const ushort* __restrict__ A, const ushort* __restrict__ Bt,
    int m0, int n0, ushort* As0, ushort* As1, ushort* Bs0, ushort* Bs1,
    floatx4 acc[4][4])
{
    const int tid  = threadIdx.x;
    const int w    = tid >> 6;
    const int lane = tid & 63;
    const int col  = lane & 15;
    const int quad = lane >> 4;
    const int wm   = w >> 1, wn = w & 1;

    #pragma unroll
    for (int i = 0; i < 4; ++i)
        #pragma unroll
        for (int j = 0; j < 4; ++j)
            acc[i][j] = (floatx4){0.f, 0.f, 0.f, 0.f};

    const int o0   = w * 2048 + lane * 16;   // byte offset in 8KB tile
    const int row0 = o0 >> 6;
    const int ke0  = (o0 & 63) >> 1;
    const int loff = (w * 2048) >> 1;        // LDS element offset for this wave

    const ushort* ga = A  + (size_t)(m0 + row0) * GK + ke0;
    const ushort* gb = Bt + (size_t)(n0 + row0) * GK + ke0;

    // prologue: stage k=0 into buffer 0
    #pragma unroll
    for (int t = 0; t < 2; ++t) {
        load_lds16(ga + (size_t)t * 16 * GK, As0 + loff + t * 512);
        load_lds16(gb + (size_t)t * 16 * GK, Bs0 + loff + t * 512);
    }
    __syncthreads();

    for (int k0 = 0; k0 < GK; k0 += 32) {
        const int cur = (k0 >> 5) & 1;
        ushort* Ac = cur ? As1 : As0;
        ushort* Bc = cur ? Bs1 : Bs0;
        ushort* An = cur ? As0 : As1;
        ushort* Bn = cur ? Bs0 : Bs1;

        if (k0 + 32 < GK) {   // issue prefetch BEFORE compute
            #pragma unroll
            for (int t = 0; t < 2; ++t) {
                load_lds16(ga + (k0 + 32) + (size_t)t * 16 * GK, An + loff + t * 512);
                load_lds16(gb + (k0 + 32) + (size_t)t * 16 * GK, Bn + loff + t * 512);
            }
        }

        short8 af[4], bf[4];
        #pragma unroll
        for (int i = 0; i < 4; ++i)
            af[i] = *(const short8*)&Ac[(wm * 64 + i * 16 + col) * 32 + quad * 8];
        #pragma unroll
        for (int j = 0; j < 4; ++j)
            bf[j] = *(const short8*)&Bc[(wn * 64 + j * 16 + col) * 32 + quad * 8];
        #pragma unroll
        for (int i = 0; i < 4; ++i)
            #pragma unroll
            for (int j = 0; j < 4; ++j)
                acc[i][j] = __builtin_amdgcn_mfma_f32_16x16x32_bf16(af[i], bf[j], acc[i][j], 0, 0, 0);

        __syncthreads();   // prefetch landed (covered by the MFMAs above);
                           // also fences cur-buffer reuse two iters later
    }
}

// ---------------------------------------------------------------------------
// 128x64 core, BK=128 (round 13; gemm_out only). r12 validated the lever:
// per-K-step barrier+drain count is the cost driver for under-occupied GEMMs
// (r6: more blocks/same steps = worse; r12: same blocks/fewer steps = +13%),
// and TLP beyond ~1-2 blocks/CU is non-binding here (r3<->r6: 1/CU == 2/CU).
// BK=128 halves steps again 16 -> 8. LDS 96KB -> 1 block/CU (expected
// neutral per r3/r6). Per step: 12 staging loads, 24 ds_reads, 32 MFMA/wave.
//   Swizzle (256B rows, 16 chunks of 16B): linear slot s of row r holds
//   logical chunk s ^ (r&15); stage source chunk (t&15)^((t>>4)&15)
//   (16-thread groups read one permuted 256B row -> coalescing kept);
//   read slot ((kk*4+quad) ^ col). Same family as r3/r12 (measured ~0 confl).
// ---------------------------------------------------------------------------
__device__ __forceinline__ void gemm_core64(
    const ushort* __restrict__ A, const ushort* __restrict__ Bt,
    int m0, int n0, ushort* As0, ushort* As1, ushort* Bs0, ushort* Bs1,
    floatx4 acc[4][2])
{
    const int tid  = threadIdx.x;
    const int w    = tid >> 6;
    const int lane = tid & 63;
    const int col  = lane & 15;
    const int quad = lane >> 4;
    const int wm   = w >> 1, wn = w & 1;

    #pragma unroll
    for (int i = 0; i < 4; ++i)
        #pragma unroll
        for (int j = 0; j < 2; ++j)
            acc[i][j] = (floatx4){0.f, 0.f, 0.f, 0.f};

    // staging: pass = 256 threads x 16B = 4KB = 16 rows of 256B.
    // thread t -> row t>>4, slot t&15; source chunk = (t&15) ^ ((t>>4)&15).
    const int srow = tid >> 4;
    const int sc   = ((tid & 15) ^ ((tid >> 4) & 15)) * 8;   // ushorts
    const int loff = w * 512;   // per-wave LDS base within a pass (ushorts)

    const ushort* ga = A  + (size_t)(m0 + srow) * GK + sc;   // A: 8 passes
    const ushort* gb = Bt + (size_t)(n0 + srow) * GK + sc;   // B: 4 passes

    // prologue: stage k=0 into buffer 0
    #pragma unroll
    for (int p = 0; p < 8; ++p)
        load_lds16(ga + (size_t)p * 16 * GK, As0 + p * 2048 + loff);
    #pragma unroll
    for (int p = 0; p < 4; ++p)
        load_lds16(gb + (size_t)p * 16 * GK, Bs0 + p * 2048 + loff);
    __syncthreads();

    // swizzled read slots for kk=0..3 (row&15 == col for all fragment rows)
    int rq[4];
    #pragma unroll
    for (int kk = 0; kk < 4; ++kk)
        rq[kk] = ((kk * 4 + quad) ^ col) * 8;   // ushorts

    for (int k0 = 0; k0 < GK; k0 += 128) {
        const int cur = (k0 >> 7) & 1;
        ushort* Ac = cur ? As1 : As0;
        ushort* Bc = cur ? Bs1 : Bs0;
        ushort* An = cur ? As0 : As1;
        ushort* Bn = cur ? Bs0 : Bs1;

        if (k0 + 128 < GK) {   // issue prefetch BEFORE compute
            #pragma unroll
            for (int p = 0; p < 8; ++p)
                load_lds16(ga + (k0 + 128) + (size_t)p * 16 * GK, An + p * 2048 + loff);
            #pragma unroll
            for (int p = 0; p < 4; ++p)
                load_lds16(gb + (k0 + 128) + (size_t)p * 16 * GK, Bn + p * 2048 + loff);
        }

        short8 af[4][4], bf[2][4];
        #pragma unroll
        for (int i = 0; i < 4; ++i) {
            const int r = (wm * 64 + i * 16 + col) * 128;   // row stride 128 ush
            #pragma unroll
            for (int kk = 0; kk < 4; ++kk)
                af[i][kk] = *(const short8*)&Ac[r + rq[kk]];
        }
        #pragma unroll
        for (int j = 0; j < 2; ++j) {
            const int r = (wn * 32 + j * 16 + col) * 128;
            #pragma unroll
            for (int kk = 0; kk < 4; ++kk)
                bf[j][kk] = *(const short8*)&Bc[r + rq[kk]];
        }
        #pragma unroll
        for (int i = 0; i < 4; ++i)
            #pragma unroll
            for (int j = 0; j < 2; ++j)
                #pragma unroll
                for (int kk = 0; kk < 4; ++kk)
                    acc[i][j] = __builtin_amdgcn_mfma_f32_16x16x32_bf16(af[i][kk], bf[j][kk], acc[i][j], 0, 0, 0);

        __syncthreads();   // prefetch landed (covered by MFMAs above);
                           // fences cur-buffer reuse two iters later
    }
}

// GEMM1: qkv projection; fused split/cast; V emitted transposed. (128x128)
// Round 13: V-part epilogue packs the 4 contiguous r-values (r -> s, stride
// 1 in Vt) into ONE 8B store — per-thread stores 64 -> 40, bitwise-identical.
__global__ __launch_bounds__(256) void gemm_qkv_mfma(
    const ushort* __restrict__ A, const ushort* __restrict__ Bt,
    const float* __restrict__ bias,
    ushort* __restrict__ Qb, ushort* __restrict__ Kb, ushort* __restrict__ Vt)
{
    __shared__ __align__(16) ushort As[2][128 * 32];
    __shared__ __align__(16) ushort Bs[2][128 * 32];
    const int n0 = blockIdx.x * 128;
    const int m0 = blockIdx.y * 128;

    floatx4 acc[4][4];
    gemm_core(A, Bt, m0, n0, As[0], As[1], Bs[0], Bs[1], acc);

    const int lane = threadIdx.x & 63;
    const int w    = threadIdx.x >> 6;
    const int col  = lane & 15, quad = lane >> 4;
    const int wm   = w >> 1, wn = w & 1;

    #pragma unroll
    for (int j = 0; j < 4; ++j) {
        const int n = n0 + wn * 64 + j * 16 + col;
        const float bj = bias[n];
        const int part = n >> 10;            // block-uniform (1024 % 128 == 0)
        const int h = (n >> 6) & 15;
        const int d = n & 63;
        #pragma unroll
        for (int i = 0; i < 4; ++i) {
            const int m = m0 + wm * 64 + i * 16 + quad * 4;   // r = 0 row
            const int b = m >> 11, s = m & 2047;
            const int bh = b * 16 + h;
            if (part == 2) {
                // r -> s contiguous: one 8B store (8B-aligned: s % 4 == 0)
                ushort4 pv = { f2bf(acc[i][j][0] + bj), f2bf(acc[i][j][1] + bj),
                               f2bf(acc[i][j][2] + bj), f2bf(acc[i][j][3] + bj) };
                *(ushort4*)&Vt[((size_t)bh * 64 + d) * SEQ + s] = pv;
            } else {
                ushort* dst = (part == 0) ? Qb : Kb;
                #pragma unroll
                for (int r = 0; r < 4; ++r)
                    dst[((size_t)bh * SEQ + s + r) * 64 + d] = f2bf(acc[i][j][r] + bj);
            }
        }
    }
}

// GEMM2: out = attn_b @ W_out + b_out -> fp32 (128x64 core, BK=128, 1/CU)
__global__ __launch_bounds__(256) void gemm_out_mfma(
    const ushort* __restrict__ A, const ushort* __restrict__ Bt,
    const float* __restrict__ bias, float* __restrict__ out)
{
    __shared__ __align__(16) ushort As[2][128 * 128];   // 64 KB
    __shared__ __align__(16) ushort Bs[2][64 * 128];    // 32 KB
    const int n0 = blockIdx.x * 64;
    const int m0 = blockIdx.y * 128;

    floatx4 acc[4][2];
    gemm_core64(A, Bt, m0, n0, As[0], As[1], Bs[0], Bs[1], acc);

    const int lane = threadIdx.x & 63;
    const int w    = threadIdx.x >> 6;
    const int col  = lane & 15, quad = lane >> 4;
    const int wm   = w >> 1, wn = w & 1;

    #pragma unroll
    for (int j = 0; j < 2; ++j) {
        const int n = n0 + wn * 32 + j * 16 + col;
        const float bj = bias[n];
        #pragma unroll
        for (int i = 0; i < 4; ++i)
            #pragma unroll
            for (int r = 0; r < 4; ++r) {
                const int m = m0 + wm * 64 + i * 16 + quad * 4 + r;
                out[(size_t)m * EMBED_DIM + n] = acc[i][j][r] + bj;
            }
    }
}

// ---------------------------------------------------------------------------
// Flash attention — r7 configuration, best measured (~47us). Untouched.
// ---------------------------------------------------------------------------
#define LP 72

__global__ __launch_bounds__(256) void attn_fused(
    const ushort* __restrict__ Qb, const ushort* __restrict__ Kb,
    const ushort* __restrict__ Vt, ushort* __restrict__ out)
{
    const int id = blockIdx.x;
    const int qt = 31 - (id >> 5);          // reversed: long blocks first (LPT)
    const int bh = id & 31;
    const int b  = bh >> 4, h = bh & 15;
    const int q0 = qt * 64;

    __shared__ __align__(16) ushort Qs[8 * 512];        // 8 KB fragment order
    __shared__ __align__(16) ushort Ks[2][8 * 512];     // 16 KB dbuf
    __shared__ __align__(16) ushort Vs[2][8 * 512];     // 16 KB dbuf
    __shared__ __align__(16) ushort Ps[64 * LP];        // 9 KB
    __shared__ __align__(16) float  ls[4][16];

    const int tid  = threadIdx.x;
    const int w    = tid >> 6;
    const int lane = tid & 63;
    const int col  = lane & 15;
    const int quad = lane >> 4;

    // per-lane global staging pointers (fragment-order gather)
    const ushort* kg[2];
    const ushort* vg[2];
    #pragma unroll
    for (int t = 0; t < 2; ++t) {
        kg[t] = Kb + (size_t)bh * SEQ * 64 + (size_t)(w * 16 + col) * 64 + t * 32 + quad * 8;
        vg[t] = Vt + (size_t)bh * 64 * SEQ + (size_t)(w * 16 + col) * SEQ + t * 32 + quad * 8;
    }

    // prologue: stage Q + K/V tile 0 into buffer 0
    {
        const ushort* Qg = Qb + ((size_t)bh * SEQ + q0) * 64;
        #pragma unroll
        for (int t = 0; t < 2; ++t) {
            load_lds16(Qg + (size_t)(w * 16 + col) * 64 + t * 32 + quad * 8,
                       &Qs[(w * 2 + t) * 512]);
            load_lds16(kg[t], &Ks[0][(w * 2 + t) * 512]);
            load_lds16(vg[t], &Vs[0][(w * 2 + t) * 512]);
            kg[t] += 64 * 64;   // -> tile 1
            vg[t] += 64;
        }
    }
    __syncthreads();

    const short8 a0 = *(const short8*)&Qs[(w * 2 + 0) * 512 + lane * 8];
    const short8 a1 = *(const short8*)&Qs[(w * 2 + 1) * 512 + lane * 8];

    floatx4 acc_o[4];
    #pragma unroll
    for (int dbi = 0; dbi < 4; ++dbi) acc_o[dbi] = (floatx4){0.f, 0.f, 0.f, 0.f};
    float l_lane = 0.f;
    const int myq = w * 16 + col;           // tile-local query owned in S^T

    for (int kt = 0; kt <= qt; ++kt) {
        const int cur = kt & 1;
        const ushort* Kc = Ks[cur];
        const ushort* Vc = Vs[cur];

        if (kt < qt) {   // issue-early prefetch of next tile into other buffer
            ushort* Kn = (ushort*)Ks[cur ^ 1];
            ushort* Vn = (ushort*)Vs[cur ^ 1];
            #pragma unroll
            for (int t = 0; t < 2; ++t) {
                load_lds16(kg[t], &Kn[(w * 2 + t) * 512]);
                load_lds16(vg[t], &Vn[(w * 2 + t) * 512]);
                kg[t] += 64 * 64;
                vg[t] += 64;
            }
        }

        // ---- S^T = K Q^T ----
        floatx4 s_acc[4];
        #pragma unroll
        for (int kb = 0; kb < 4; ++kb) {
            short8 k0f = *(const short8*)&Kc[(kb * 2 + 0) * 512 + lane * 8];
            short8 k1f = *(const short8*)&Kc[(kb * 2 + 1) * 512 + lane * 8];
            floatx4 z = (floatx4){0.f, 0.f, 0.f, 0.f};
            z = __builtin_amdgcn_mfma_f32_16x16x32_bf16(k0f, a0, z, 0, 0, 0);
            z = __builtin_amdgcn_mfma_f32_16x16x32_bf16(k1f, a1, z, 0, 0, 0);
            s_acc[kb] = z;   // lane: query col; regs: keys kb*16+quad*4+r
        }

        // ---- p = exp(s/8); write P rows (ds_write_b64 each) ----
        if (kt == qt) {
            #pragma unroll
            for (int kb = 0; kb < 4; ++kb) {
                const int kbase = kb * 16 + quad * 4;
                float p[4];
                #pragma unroll
                for (int r = 0; r < 4; ++r) {
                    float e = __expf(s_acc[kb][r] * 0.125f);
                    p[r] = (kbase + r > myq) ? 0.f : e;
                    l_lane += p[r];
                }
                uint2 u = { bfpack2(p[0], p[1]), bfpack2(p[2], p[3]) };
                *(uint2*)&Ps[myq * LP + kbase] = u;
            }
        } else {
            #pragma unroll
            for (int kb = 0; kb < 4; ++kb) {
                const int kbase = kb * 16 + quad * 4;
                float p[4];
                #pragma unroll
                for (int r = 0; r < 4; ++r) {
                    p[r] = __expf(s_acc[kb][r] * 0.125f);
                    l_lane += p[r];
                }
                uint2 u = { bfpack2(p[0], p[1]), bfpack2(p[2], p[3]) };
                *(uint2*)&Ps[myq * LP + kbase] = u;
            }
        }

        // ---- O += P V  (Ps rows wave-private) ----
        short8 pa0 = *(const short8*)&Ps[(w * 16 + col) * LP + quad * 8];
        short8 pa1 = *(const short8*)&Ps[(w * 16 + col) * LP + 32 + quad * 8];
        #pragma unroll
        for (int dbi = 0; dbi < 4; ++dbi) {
            short8 vb0 = *(const short8*)&Vc[(dbi * 2 + 0) * 512 + lane * 8];
            short8 vb1 = *(const short8*)&Vc[(dbi * 2 + 1) * 512 + lane * 8];
            acc_o[dbi] = __builtin_amdgcn_mfma_f32_16x16x32_bf16(pa0, vb0, acc_o[dbi], 0, 0, 0);
            acc_o[dbi] = __builtin_amdgcn_mfma_f32_16x16x32_bf16(pa1, vb1, acc_o[dbi], 0, 0, 0);
        }

        __syncthreads();   // prefetch landed (covered by compute above);
                           // fences cur-buffer overwrite two iters later
    }

    // ---- finalize l ----
    l_lane += __shfl_xor(l_lane, 16);
    l_lane += __shfl_xor(l_lane, 32);
    if (quad == 0) ls[w][col] = 1.f / l_lane;   // wave-private
    float4 invv = *(const float4*)&ls[w][quad * 4];

    #pragma unroll
    for (int dbi = 0; dbi < 4; ++dbi)
        #pragma unroll
        for (int r = 0; r < 4; ++r) {
            int q = q0 + w * 16 + quad * 4 + r;
            int d = dbi * 16 + col;
            float inv = (r == 0) ? invv.x : (r == 1) ? invv.y : (r == 2) ? invv.z : invv.w;
            out[((size_t)(b * SEQ + q)) * EMBED_DIM + h * 64 + d] = f2bf(acc_o[dbi][r] * inv);
        }
}

// ---------------------------------------------------------------------------
extern "C" void kernel_launch(void* const* d_in, const int* in_sizes, int n_in,
                              void* d_out, int out_size, void* d_ws, size_t ws_size,
                              hipStream_t stream)
{
    const float* x     = (const float*)d_in[0];
    const float* W_qkv = (const float*)d_in[1];
    const float* b_qkv = (const float*)d_in[2];
    const float* W_out = (const float*)d_in[3];
    const float* b_out = (const float*)d_in[4];
    float* out = (float*)d_out;

    const int M  = BATCH * SEQ;            // 4096
    const int D  = EMBED_DIM;              // 1024
    const int N1 = 3 * D;                  // 3072
    const size_t HE = (size_t)BATCH * NUM_HEADS * SEQ * 64;  // 4M

    ushort* xb    = (ushort*)d_ws;
    ushort* Wqb_t = xb + (size_t)M * D;
    ushort* Wob_t = Wqb_t + (size_t)D * N1;
    ushort* Qb    = Wob_t + (size_t)D * D;
    ushort* Kb    = Qb + HE;
    ushort* Vt    = Kb + HE;
    ushort* attnb = Vt + HE;

    // 0) fused prep: cast x, transpose+cast weights
    prep_all<<<5120, 256, 0, stream>>>(x, W_qkv, W_out, xb, Wqb_t, Wob_t);

    // 1) qkv projection — 128x128 (round-0 best) + packed V stores
    gemm_qkv_mfma<<<dim3(N1 / 128, M / 128), 256, 0, stream>>>(
        xb, Wqb_t, b_qkv, Qb, Kb, Vt);

    // 2) flash attention — staged v1 (r7 best), 1024 blocks = 3/CU
    attn_fused<<<dim3(32 * 32), 256, 0, stream>>>(Qb, Kb, Vt, attnb);

    // 3) output projection — 128x64, BK=128 (8 K-steps), 512 blocks = 1/CU
    gemm_out_mfma<<<dim3(D / 64, M / 128), 256, 0, stream>>>(
        attnb, Wob_t, b_out, out);
}

// Round 14
// 185.974 us; speedup vs baseline: 1.0541x; 1.0541x over previous
//
#include <hip/hip_runtime.h>
#include <hip/hip_bf16.h>
#include <math.h>

#define EMBED_DIM 1024
#define NUM_HEADS 16
#define HEAD_DIM 64
#define BATCH 2
#define SEQ 2048

using short8  = __attribute__((ext_vector_type(8))) short;
using floatx4 = __attribute__((ext_vector_type(4))) float;

__device__ __forceinline__ ushort f2bf(float f) {
    unsigned u = __float_as_uint(f);
    u = (u + 0x7FFFu + ((u >> 16) & 1u)) >> 16;   // RNE
    return (ushort)u;
}

// pack two floats to bf16x2 (half-up rounding — P values are in [0,1], fine)
__device__ __forceinline__ unsigned bfpack2(float a, float b) {
    return ((__float_as_uint(a) + 0x8000u) >> 16) |
           (((__float_as_uint(b) + 0x8000u) >> 16) << 16);
}

// async global->LDS, 16B per lane; LDS dest = wave-uniform base + lane*16.
__device__ __forceinline__ void load_lds16(const ushort* g, ushort* l) {
    __builtin_amdgcn_global_load_lds(
        (const __attribute__((address_space(1))) void*)g,
        (__attribute__((address_space(3))) void*)l, 16, 0, 0);
}

// ---------------------------------------------------------------------------
// Fused prep: cast x -> bf16, transpose+cast W_qkv and W_out.
// ---------------------------------------------------------------------------
__device__ __forceinline__ void tc_tile(
    const float* __restrict__ W, ushort* __restrict__ Wt,
    int K, int N, int n0, int k0, float (*t)[65])
{
    const int c = threadIdx.x & 63, r0 = (threadIdx.x >> 6) * 16;
    #pragma unroll
    for (int r = 0; r < 16; ++r)
        t[r0 + r][c] = W[(size_t)(k0 + r0 + r) * N + n0 + c];
    __syncthreads();
    #pragma unroll
    for (int r = 0; r < 16; ++r)
        Wt[(size_t)(n0 + r0 + r) * K + k0 + c] = f2bf(t[c][r0 + r]);
}

__global__ __launch_bounds__(256) void prep_all(
    const float* __restrict__ x, const float* __restrict__ W_qkv,
    const float* __restrict__ W_out,
    ushort* __restrict__ xb, ushort* __restrict__ Wqb_t, ushort* __restrict__ Wob_t)
{
    __shared__ float t[64][65];
    const int bx = blockIdx.x;
    if (bx < 4096) {
        int i = (bx * 256 + threadIdx.x) * 4;
        float4 v = *(const float4*)&x[i];
        ushort4 o = { f2bf(v.x), f2bf(v.y), f2bf(v.z), f2bf(v.w) };
        *(ushort4*)&xb[i] = o;
    } else if (bx < 4096 + 768) {
        int b = bx - 4096;
        tc_tile(W_qkv, Wqb_t, 1024, 3072, (b % 48) * 64, (b / 48) * 64, t);
    } else {
        int b = bx - 4864;
        tc_tile(W_out, Wob_t, 1024, 1024, (b % 16) * 64, (b / 16) * 64, t);
    }
}

// ---------------------------------------------------------------------------
// bf16 MFMA GEMM core, 128x128, double-buffered — round-0 best (46.5us).
// Measured local optimum (rounds 1-6). Parked; used by gemm_qkv only.
// ---------------------------------------------------------------------------
#define GK 1024

__device__ __forceinline__ void gemm_core(
    const ushort* __restrict__ A, const ushort* __restrict__ Bt,
    int m0, int n0, ushort* As0, ushort* As1, ushort* Bs0, ushort* Bs1,
    floatx4 acc[4][4])
{
    const int tid  = threadIdx.x;
    const int w    = tid >> 6;
    const int lane = tid & 63;
    const int col  = lane & 15;
    const int quad = lane >> 4;
    const int wm   = w >> 1, wn = w & 1;

    #pragma unroll
    for (int i = 0; i < 4; ++i)
        #pragma unroll
        for (int j = 0; j < 4; ++j)
            acc[i][j] = (floatx4){0.f, 0.f, 0.f, 0.f};

    const int o0   = w * 2048 + lane * 16;   // byte offset in 8KB tile
    const int row0 = o0 >> 6;
    const int ke0  = (o0 & 63) >> 1;
    const int loff = (w * 2048) >> 1;        // LDS element offset for this wave

    const ushort* ga = A  + (size_t)(m0 + row0) * GK + ke0;
    const ushort* gb = Bt + (size_t)(n0 + row0) * GK + ke0;

    // prologue: stage k=0 into buffer 0
    #pragma unroll
    for (int t = 0; t < 2; ++t) {
        load_lds16(ga + (size_t)t * 16 * GK, As0 + loff + t * 512);
        load_lds16(gb + (size_t)t * 16 * GK, Bs0 + loff + t * 512);
    }
    __syncthreads();

    for (int k0 = 0; k0 < GK; k0 += 32) {
        const int cur = (k0 >> 5) & 1;
        ushort* Ac = cur ? As1 : As0;
        ushort* Bc = cur ? Bs1 : Bs0;
        ushort* An = cur ? As0 : As1;
        ushort* Bn = cur ? Bs0 : Bs1;

        if (k0 + 32 < GK) {   // issue prefetch BEFORE compute
            #pragma unroll
            for (int t = 0; t < 2; ++t) {
                load_lds16(ga + (k0 + 32) + (size_t)t * 16 * GK, An + loff + t * 512);
                load_lds16(gb + (k0 + 32) + (size_t)t * 16 * GK, Bn + loff + t * 512);
            }
        }

        short8 af[4], bf[4];
        #pragma unroll
        for (int i = 0; i < 4; ++i)
            af[i] = *(const short8*)&Ac[(wm * 64 + i * 16 + col) * 32 + quad * 8];
        #pragma unroll
        for (int j = 0; j < 4; ++j)
            bf[j] = *(const short8*)&Bc[(wn * 64 + j * 16 + col) * 32 + quad * 8];
        #pragma unroll
        for (int i = 0; i < 4; ++i)
            #pragma unroll
            for (int j = 0; j < 4; ++j)
                acc[i][j] = __builtin_amdgcn_mfma_f32_16x16x32_bf16(af[i], bf[j], acc[i][j], 0, 0, 0);

        __syncthreads();   // prefetch landed (covered by the MFMAs above);
                           // also fences cur-buffer reuse two iters later
    }
}

// ---------------------------------------------------------------------------
// 128x64 core, BK=64 (gemm_out only). r12-validated: per-K-step barrier+drain
// count is the cost driver for under-occupied GEMMs (r6: more blocks/same
// steps = worse; r12: same blocks/half steps = +13%; r13: BK=128 at 1/CU
// = worse). BK=64, 16 steps, 48KB LDS, 2 blocks/CU.
//   Swizzle (128B rows): linear 16B-chunk c of row r holds logical
//   c ^ (r&7); stage source chunk (l&7)^(l>>3); reads ((kk*4+quad)^(col&7)).
// ---------------------------------------------------------------------------
__device__ __forceinline__ void gemm_core64(
    const ushort* __restrict__ A, const ushort* __restrict__ Bt,
    int m0, int n0, ushort* As0, ushort* As1, ushort* Bs0, ushort* Bs1,
    floatx4 acc[4][2])
{
    const int tid  = threadIdx.x;
    const int w    = tid >> 6;
    const int lane = tid & 63;
    const int col  = lane & 15;
    const int quad = lane >> 4;
    const int wm   = w >> 1, wn = w & 1;

    #pragma unroll
    for (int i = 0; i < 4; ++i)
        #pragma unroll
        for (int j = 0; j < 2; ++j)
            acc[i][j] = (floatx4){0.f, 0.f, 0.f, 0.f};

    // staging: pass = 4KB = 32 rows of 128B; lane -> row w*8+(l>>3), chunk l&7
    const int srow = w * 8 + (lane >> 3);
    const int sc   = ((lane & 7) ^ (lane >> 3)) * 8;   // swizzled source chunk
    const int loff = w * 512;                          // ushort wave base / pass

    const ushort* ga = A  + (size_t)(m0 + srow) * GK + sc;
    const ushort* gb = Bt + (size_t)(n0 + srow) * GK + sc;

    // prologue: stage k=0 into buffer 0 (A: 4 passes, B: 2 passes)
    #pragma unroll
    for (int p = 0; p < 4; ++p)
        load_lds16(ga + (size_t)p * 32 * GK, As0 + p * 2048 + loff);
    #pragma unroll
    for (int p = 0; p < 2; ++p)
        load_lds16(gb + (size_t)p * 32 * GK, Bs0 + p * 2048 + loff);
    __syncthreads();

    // swizzled read chunks for kk=0,1 (row&7 == col&7 for all fragment rows)
    const int c7  = col & 7;
    const int rq0 = (quad ^ c7) * 8;
    const int rq1 = ((4 + quad) ^ c7) * 8;

    for (int k0 = 0; k0 < GK; k0 += 64) {
        const int cur = (k0 >> 6) & 1;
        ushort* Ac = cur ? As1 : As0;
        ushort* Bc = cur ? Bs1 : Bs0;
        ushort* An = cur ? As0 : As1;
        ushort* Bn = cur ? Bs0 : Bs1;

        if (k0 + 64 < GK) {   // issue prefetch BEFORE compute
            #pragma unroll
            for (int p = 0; p < 4; ++p)
                load_lds16(ga + (k0 + 64) + (size_t)p * 32 * GK, An + p * 2048 + loff);
            #pragma unroll
            for (int p = 0; p < 2; ++p)
                load_lds16(gb + (k0 + 64) + (size_t)p * 32 * GK, Bn + p * 2048 + loff);
        }

        short8 af[4][2], bf[2][2];
        #pragma unroll
        for (int i = 0; i < 4; ++i) {
            const int r = (wm * 64 + i * 16 + col) * 64;
            af[i][0] = *(const short8*)&Ac[r + rq0];
            af[i][1] = *(const short8*)&Ac[r + rq1];
        }
        #pragma unroll
        for (int j = 0; j < 2; ++j) {
            const int r = (wn * 32 + j * 16 + col) * 64;
            bf[j][0] = *(const short8*)&Bc[r + rq0];
            bf[j][1] = *(const short8*)&Bc[r + rq1];
        }
        #pragma unroll
        for (int i = 0; i < 4; ++i)
            #pragma unroll
            for (int j = 0; j < 2; ++j) {
                acc[i][j] = __builtin_amdgcn_mfma_f32_16x16x32_bf16(af[i][0], bf[j][0], acc[i][j], 0, 0, 0);
                acc[i][j] = __builtin_amdgcn_mfma_f32_16x16x32_bf16(af[i][1], bf[j][1], acc[i][j], 0, 0, 0);
            }

        __syncthreads();   // prefetch landed (covered by MFMAs + other block);
                           // fences cur-buffer reuse two iters later
    }
}

// GEMM1: qkv projection; fused split/cast; V emitted transposed. (128x128)
// r13 lesson: do NOT pack V stores — the wider live range costs VGPR 84->100
// and occupancy 24->15%, a net -8.5us. Scalar epilogue stays.
__global__ __launch_bounds__(256) void gemm_qkv_mfma(
    const ushort* __restrict__ A, const ushort* __restrict__ Bt,
    const float* __restrict__ bias,
    ushort* __restrict__ Qb, ushort* __restrict__ Kb, ushort* __restrict__ Vt)
{
    __shared__ __align__(16) ushort As[2][128 * 32];
    __shared__ __align__(16) ushort Bs[2][128 * 32];
    const int n0 = blockIdx.x * 128;
    const int m0 = blockIdx.y * 128;

    floatx4 acc[4][4];
    gemm_core(A, Bt, m0, n0, As[0], As[1], Bs[0], Bs[1], acc);

    const int lane = threadIdx.x & 63;
    const int w    = threadIdx.x >> 6;
    const int col  = lane & 15, quad = lane >> 4;
    const int wm   = w >> 1, wn = w & 1;

    #pragma unroll
    for (int j = 0; j < 4; ++j) {
        const int n = n0 + wn * 64 + j * 16 + col;
        const float bj = bias[n];
        const int part = n >> 10;
        const int h = (n >> 6) & 15;
        const int d = n & 63;
        #pragma unroll
        for (int i = 0; i < 4; ++i)
            #pragma unroll
            for (int r = 0; r < 4; ++r) {
                const int m = m0 + wm * 64 + i * 16 + quad * 4 + r;
                const int b = m >> 11, s = m & 2047;
                const int bh = b * 16 + h;
                const ushort bv = f2bf(acc[i][j][r] + bj);
                if (part == 0)      Qb[((size_t)bh * SEQ + s) * 64 + d] = bv;
                else if (part == 1) Kb[((size_t)bh * SEQ + s) * 64 + d] = bv;
                else                Vt[((size_t)bh * 64 + d) * SEQ + s] = bv;
            }
    }
}

// GEMM2: out = attn_b @ W_out + b_out -> fp32 (128x64 core, BK=64, 2/CU)
__global__ __launch_bounds__(256) void gemm_out_mfma(
    const ushort* __restrict__ A, const ushort* __restrict__ Bt,
    const float* __restrict__ bias, float* __restrict__ out)
{
    __shared__ __align__(16) ushort As[2][128 * 64];   // 32 KB
    __shared__ __align__(16) ushort Bs[2][64 * 64];    // 16 KB
    const int n0 = blockIdx.x * 64;
    const int m0 = blockIdx.y * 128;

    floatx4 acc[4][2];
    gemm_core64(A, Bt, m0, n0, As[0], As[1], Bs[0], Bs[1], acc);

    const int lane = threadIdx.x & 63;
    const int w    = threadIdx.x >> 6;
    const int col  = lane & 15, quad = lane >> 4;
    const int wm   = w >> 1, wn = w & 1;

    #pragma unroll
    for (int j = 0; j < 2; ++j) {
        const int n = n0 + wn * 32 + j * 16 + col;
        const float bj = bias[n];
        #pragma unroll
        for (int i = 0; i < 4; ++i)
            #pragma unroll
            for (int r = 0; r < 4; ++r) {
                const int m = m0 + wm * 64 + i * 16 + quad * 4 + r;
                out[(size_t)m * EMBED_DIM + n] = acc[i][j][r] + bj;
            }
    }
}

// ---------------------------------------------------------------------------
// Flash attention — r7 configuration, best measured (~47us). Untouched.
// ---------------------------------------------------------------------------
#define LP 72

__global__ __launch_bounds__(256) void attn_fused(
    const ushort* __restrict__ Qb, const ushort* __restrict__ Kb,
    const ushort* __restrict__ Vt, ushort* __restrict__ out)
{
    const int id = blockIdx.x;
    const int qt = 31 - (id >> 5);          // reversed: long blocks first (LPT)
    const int bh = id & 31;
    const int b  = bh >> 4, h = bh & 15;
    const int q0 = qt * 64;

    __shared__ __align__(16) ushort Qs[8 * 512];        // 8 KB fragment order
    __shared__ __align__(16) ushort Ks[2][8 * 512];     // 16 KB dbuf
    __shared__ __align__(16) ushort Vs[2][8 * 512];     // 16 KB dbuf
    __shared__ __align__(16) ushort Ps[64 * LP];        // 9 KB
    __shared__ __align__(16) float  ls[4][16];

    const int tid  = threadIdx.x;
    const int w    = tid >> 6;
    const int lane = tid & 63;
    const int col  = lane & 15;
    const int quad = lane >> 4;

    // per-lane global staging pointers (fragment-order gather)
    const ushort* kg[2];
    const ushort* vg[2];
    #pragma unroll
    for (int t = 0; t < 2; ++t) {
        kg[t] = Kb + (size_t)bh * SEQ * 64 + (size_t)(w * 16 + col) * 64 + t * 32 + quad * 8;
        vg[t] = Vt + (size_t)bh * 64 * SEQ + (size_t)(w * 16 + col) * SEQ + t * 32 + quad * 8;
    }

    // prologue: stage Q + K/V tile 0 into buffer 0
    {
        const ushort* Qg = Qb + ((size_t)bh * SEQ + q0) * 64;
        #pragma unroll
        for (int t = 0; t < 2; ++t) {
            load_lds16(Qg + (size_t)(w * 16 + col) * 64 + t * 32 + quad * 8,
                       &Qs[(w * 2 + t) * 512]);
            load_lds16(kg[t], &Ks[0][(w * 2 + t) * 512]);
            load_lds16(vg[t], &Vs[0][(w * 2 + t) * 512]);
            kg[t] += 64 * 64;   // -> tile 1
            vg[t] += 64;
        }
    }
    __syncthreads();

    const short8 a0 = *(const short8*)&Qs[(w * 2 + 0) * 512 + lane * 8];
    const short8 a1 = *(const short8*)&Qs[(w * 2 + 1) * 512 + lane * 8];

    floatx4 acc_o[4];
    #pragma unroll
    for (int dbi = 0; dbi < 4; ++dbi) acc_o[dbi] = (floatx4){0.f, 0.f, 0.f, 0.f};
    float l_lane = 0.f;
    const int myq = w * 16 + col;           // tile-local query owned in S^T

    for (int kt = 0; kt <= qt; ++kt) {
        const int cur = kt & 1;
        const ushort* Kc = Ks[cur];
        const ushort* Vc = Vs[cur];

        if (kt < qt) {   // issue-early prefetch of next tile into other buffer
            ushort* Kn = (ushort*)Ks[cur ^ 1];
            ushort* Vn = (ushort*)Vs[cur ^ 1];
            #pragma unroll
            for (int t = 0; t < 2; ++t) {
                load_lds16(kg[t], &Kn[(w * 2 + t) * 512]);
                load_lds16(vg[t], &Vn[(w * 2 + t) * 512]);
                kg[t] += 64 * 64;
                vg[t] += 64;
            }
        }

        // ---- S^T = K Q^T ----
        floatx4 s_acc[4];
        #pragma unroll
        for (int kb = 0; kb < 4; ++kb) {
            short8 k0f = *(const short8*)&Kc[(kb * 2 + 0) * 512 + lane * 8];
            short8 k1f = *(const short8*)&Kc[(kb * 2 + 1) * 512 + lane * 8];
            floatx4 z = (floatx4){0.f, 0.f, 0.f, 0.f};
            z = __builtin_amdgcn_mfma_f32_16x16x32_bf16(k0f, a0, z, 0, 0, 0);
            z = __builtin_amdgcn_mfma_f32_16x16x32_bf16(k1f, a1, z, 0, 0, 0);
            s_acc[kb] = z;   // lane: query col; regs: keys kb*16+quad*4+r
        }

        // ---- p = exp(s/8); write P rows (ds_write_b64 each) ----
        if (kt == qt) {
            #pragma unroll
            for (int kb = 0; kb < 4; ++kb) {
                const int kbase = kb * 16 + quad * 4;
                float p[4];
                #pragma unroll
                for (int r = 0; r < 4; ++r) {
                    float e = __expf(s_acc[kb][r] * 0.125f);
                    p[r] = (kbase + r > myq) ? 0.f : e;
                    l_lane += p[r];
                }
                uint2 u = { bfpack2(p[0], p[1]), bfpack2(p[2], p[3]) };
                *(uint2*)&Ps[myq * LP + kbase] = u;
            }
        } else {
            #pragma unroll
            for (int kb = 0; kb < 4; ++kb) {
                const int kbase = kb * 16 + quad * 4;
                float p[4];
                #pragma unroll
                for (int r = 0; r < 4; ++r) {
                    p[r] = __expf(s_acc[kb][r] * 0.125f);
                    l_lane += p[r];
                }
                uint2 u = { bfpack2(p[0], p[1]), bfpack2(p[2], p[3]) };
                *(uint2*)&Ps[myq * LP + kbase] = u;
            }
        }

        // ---- O += P V  (Ps rows wave-private) ----
        short8 pa0 = *(const short8*)&Ps[(w * 16 + col) * LP + quad * 8];
        short8 pa1 = *(const short8*)&Ps[(w * 16 + col) * LP + 32 + quad * 8];
        #pragma unroll
        for (int dbi = 0; dbi < 4; ++dbi) {
            short8 vb0 = *(const short8*)&Vc[(dbi * 2 + 0) * 512 + lane * 8];
            short8 vb1 = *(const short8*)&Vc[(dbi * 2 + 1) * 512 + lane * 8];
            acc_o[dbi] = __builtin_amdgcn_mfma_f32_16x16x32_bf16(pa0, vb0, acc_o[dbi], 0, 0, 0);
            acc_o[dbi] = __builtin_amdgcn_mfma_f32_16x16x32_bf16(pa1, vb1, acc_o[dbi], 0, 0, 0);
        }

        __syncthreads();   // prefetch landed (covered by compute above);
                           // fences cur-buffer overwrite two iters later
    }

    // ---- finalize l ----
    l_lane += __shfl_xor(l_lane, 16);
    l_lane += __shfl_xor(l_lane, 32);
    if (quad == 0) ls[w][col] = 1.f / l_lane;   // wave-private
    float4 invv = *(const float4*)&ls[w][quad * 4];

    #pragma unroll
    for (int dbi = 0; dbi < 4; ++dbi)
        #pragma unroll
        for (int r = 0; r < 4; ++r) {
            int q = q0 + w * 16 + quad * 4 + r;
            int d = dbi * 16 + col;
            float inv = (r == 0) ? invv.x : (r == 1) ? invv.y : (r == 2) ? invv.z : invv.w;
            out[((size_t)(b * SEQ + q)) * EMBED_DIM + h * 64 + d] = f2bf(acc_o[dbi][r] * inv);
        }
}

// ---------------------------------------------------------------------------
extern "C" void kernel_launch(void* const* d_in, const int* in_sizes, int n_in,
                              void* d_out, int out_size, void* d_ws, size_t ws_size,
                              hipStream_t stream)
{
    const float* x     = (const float*)d_in[0];
    const float* W_qkv = (const float*)d_in[1];
    const float* b_qkv = (const float*)d_in[2];
    const float* W_out = (const float*)d_in[3];
    const float* b_out = (const float*)d_in[4];
    float* out = (float*)d_out;

    const int M  = BATCH * SEQ;            // 4096
    const int D  = EMBED_DIM;              // 1024
    const int N1 = 3 * D;                  // 3072
    const size_t HE = (size_t)BATCH * NUM_HEADS * SEQ * 64;  // 4M

    ushort* xb    = (ushort*)d_ws;
    ushort* Wqb_t = xb + (size_t)M * D;
    ushort* Wob_t = Wqb_t + (size_t)D * N1;
    ushort* Qb    = Wob_t + (size_t)D * D;
    ushort* Kb    = Qb + HE;
    ushort* Vt    = Kb + HE;
    ushort* attnb = Vt + HE;

    // 0) fused prep: cast x, transpose+cast weights
    prep_all<<<5120, 256, 0, stream>>>(x, W_qkv, W_out, xb, Wqb_t, Wob_t);

    // 1) qkv projection — 128x128 (round-0 best), 768 blocks = 3/CU
    gemm_qkv_mfma<<<dim3(N1 / 128, M / 128), 256, 0, stream>>>(
        xb, Wqb_t, b_qkv, Qb, Kb, Vt);

    // 2) flash attention — staged v1 (r7 best), 1024 blocks = 3/CU
    attn_fused<<<dim3(32 * 32), 256, 0, stream>>>(Qb, Kb, Vt, attnb);

    // 3) output projection — 128x64, BK=64 (16 K-steps), 512 blocks = 2/CU
    gemm_out_mfma<<<dim3(D / 64, M / 128), 256, 0, stream>>>(
        attnb, Wob_t, b_out, out);
}

// Round 15
// 185.368 us; speedup vs baseline: 1.0575x; 1.0033x over previous
//
#include <hip/hip_runtime.h>
#include <hip/hip_bf16.h>
#include <math.h>

#define EMBED_DIM 1024
#define NUM_HEADS 16
#define HEAD_DIM 64
#define BATCH 2
#define SEQ 2048

using short8  = __attribute__((ext_vector_type(8))) short;
using floatx4 = __attribute__((ext_vector_type(4))) float;

__device__ __forceinline__ ushort f2bf(float f) {
    unsigned u = __float_as_uint(f);
    u = (u + 0x7FFFu + ((u >> 16) & 1u)) >> 16;   // RNE
    return (ushort)u;
}

// pack two floats to bf16x2 (half-up rounding — P values are in [0,1], fine)
__device__ __forceinline__ unsigned bfpack2(float a, float b) {
    return ((__float_as_uint(a) + 0x8000u) >> 16) |
           (((__float_as_uint(b) + 0x8000u) >> 16) << 16);
}

// async global->LDS, 16B per lane; LDS dest = wave-uniform base + lane*16.
__device__ __forceinline__ void load_lds16(const ushort* g, ushort* l) {
    __builtin_amdgcn_global_load_lds(
        (const __attribute__((address_space(1))) void*)g,
        (__attribute__((address_space(3))) void*)l, 16, 0, 0);
}

// ---------------------------------------------------------------------------
// Fused prep: cast x -> bf16, transpose+cast W_qkv and W_out.
// ---------------------------------------------------------------------------
__device__ __forceinline__ void tc_tile(
    const float* __restrict__ W, ushort* __restrict__ Wt,
    int K, int N, int n0, int k0, float (*t)[65])
{
    const int c = threadIdx.x & 63, r0 = (threadIdx.x >> 6) * 16;
    #pragma unroll
    for (int r = 0; r < 16; ++r)
        t[r0 + r][c] = W[(size_t)(k0 + r0 + r) * N + n0 + c];
    __syncthreads();
    #pragma unroll
    for (int r = 0; r < 16; ++r)
        Wt[(size_t)(n0 + r0 + r) * K + k0 + c] = f2bf(t[c][r0 + r]);
}

__global__ __launch_bounds__(256) void prep_all(
    const float* __restrict__ x, const float* __restrict__ W_qkv,
    const float* __restrict__ W_out,
    ushort* __restrict__ xb, ushort* __restrict__ Wqb_t, ushort* __restrict__ Wob_t)
{
    __shared__ float t[64][65];
    const int bx = blockIdx.x;
    if (bx < 4096) {
        int i = (bx * 256 + threadIdx.x) * 4;
        float4 v = *(const float4*)&x[i];
        ushort4 o = { f2bf(v.x), f2bf(v.y), f2bf(v.z), f2bf(v.w) };
        *(ushort4*)&xb[i] = o;
    } else if (bx < 4096 + 768) {
        int b = bx - 4096;
        tc_tile(W_qkv, Wqb_t, 1024, 3072, (b % 48) * 64, (b / 48) * 64, t);
    } else {
        int b = bx - 4864;
        tc_tile(W_out, Wob_t, 1024, 1024, (b % 16) * 64, (b / 16) * 64, t);
    }
}

// ---------------------------------------------------------------------------
// bf16 MFMA GEMM core, 128x128, double-buffered — round-0 best (46.5us).
// Measured local optimum (rounds 1-6): swizzle/schedule/tile/occupancy
// perturbations all null or negative. The binding constraint is the 2-phase
// per-K-step DMA-drain + barrier; the escape (8-phase counted-vmcnt) did not
// reproduce at HIP source level in 3 attempts (r1-r3, all ~3x floor).
// ---------------------------------------------------------------------------
#define GK 1024

__device__ __forceinline__ void gemm_core(
    const ushort* __restrict__ A, const ushort* __restrict__ Bt,
    int m0, int n0, ushort* As0, ushort* As1, ushort* Bs0, ushort* Bs1,
    floatx4 acc[4][4])
{
    const int tid  = threadIdx.x;
    const int w    = tid >> 6;
    const int lane = tid & 63;
    const int col  = lane & 15;
    const int quad = lane >> 4;
    const int wm   = w >> 1, wn = w & 1;

    #pragma unroll
    for (int i = 0; i < 4; ++i)
        #pragma unroll
        for (int j = 0; j < 4; ++j)
            acc[i][j] = (floatx4){0.f, 0.f, 0.f, 0.f};

    const int o0   = w * 2048 + lane * 16;   // byte offset in 8KB tile
    const int row0 = o0 >> 6;
    const int ke0  = (o0 & 63) >> 1;
    const int loff = (w * 2048) >> 1;        // LDS element offset for this wave

    const ushort* ga = A  + (size_t)(m0 + row0) * GK + ke0;
    const ushort* gb = Bt + (size_t)(n0 + row0) * GK + ke0;

    // prologue: stage k=0 into buffer 0
    #pragma unroll
    for (int t = 0; t < 2; ++t) {
        load_lds16(ga + (size_t)t * 16 * GK, As0 + loff + t * 512);
        load_lds16(gb + (size_t)t * 16 * GK, Bs0 + loff + t * 512);
    }
    __syncthreads();

    for (int k0 = 0; k0 < GK; k0 += 32) {
        const int cur = (k0 >> 5) & 1;
        ushort* Ac = cur ? As1 : As0;
        ushort* Bc = cur ? Bs1 : Bs0;
        ushort* An = cur ? As0 : As1;
        ushort* Bn = cur ? Bs0 : Bs1;

        if (k0 + 32 < GK) {   // issue prefetch BEFORE compute
            #pragma unroll
            for (int t = 0; t < 2; ++t) {
                load_lds16(ga + (k0 + 32) + (size_t)t * 16 * GK, An + loff + t * 512);
                load_lds16(gb + (k0 + 32) + (size_t)t * 16 * GK, Bn + loff + t * 512);
            }
        }

        short8 af[4], bf[4];
        #pragma unroll
        for (int i = 0; i < 4; ++i)
            af[i] = *(const short8*)&Ac[(wm * 64 + i * 16 + col) * 32 + quad * 8];
        #pragma unroll
        for (int j = 0; j < 4; ++j)
            bf[j] = *(const short8*)&Bc[(wn * 64 + j * 16 + col) * 32 + quad * 8];
        #pragma unroll
        for (int i = 0; i < 4; ++i)
            #pragma unroll
            for (int j = 0; j < 4; ++j)
                acc[i][j] = __builtin_amdgcn_mfma_f32_16x16x32_bf16(af[i], bf[j], acc[i][j], 0, 0, 0);

        __syncthreads();   // prefetch landed (covered by the MFMAs above);
                           // also fences cur-buffer reuse two iters later
    }
}

// ---------------------------------------------------------------------------
// 128x64 core, BK=64 (gemm_out only). r12-validated: per-K-step barrier+drain
// count is the cost driver for under-occupied GEMMs (r6: more blocks/same
// steps = worse; r12: same blocks/half steps = +13%; r13: BK=128 at 1/CU
// = worse). BK=64, 16 steps, 48KB LDS, 2 blocks/CU.
//   Swizzle (128B rows): linear 16B-chunk c of row r holds logical
//   c ^ (r&7); stage source chunk (l&7)^(l>>3); reads ((kk*4+quad)^(col&7)).
// ---------------------------------------------------------------------------
__device__ __forceinline__ void gemm_core64(
    const ushort* __restrict__ A, const ushort* __restrict__ Bt,
    int m0, int n0, ushort* As0, ushort* As1, ushort* Bs0, ushort* Bs1,
    floatx4 acc[4][2])
{
    const int tid  = threadIdx.x;
    const int w    = tid >> 6;
    const int lane = tid & 63;
    const int col  = lane & 15;
    const int quad = lane >> 4;
    const int wm   = w >> 1, wn = w & 1;

    #pragma unroll
    for (int i = 0; i < 4; ++i)
        #pragma unroll
        for (int j = 0; j < 2; ++j)
            acc[i][j] = (floatx4){0.f, 0.f, 0.f, 0.f};

    // staging: pass = 4KB = 32 rows of 128B; lane -> row w*8+(l>>3), chunk l&7
    const int srow = w * 8 + (lane >> 3);
    const int sc   = ((lane & 7) ^ (lane >> 3)) * 8;   // swizzled source chunk
    const int loff = w * 512;                          // ushort wave base / pass

    const ushort* ga = A  + (size_t)(m0 + srow) * GK + sc;
    const ushort* gb = Bt + (size_t)(n0 + srow) * GK + sc;

    // prologue: stage k=0 into buffer 0 (A: 4 passes, B: 2 passes)
    #pragma unroll
    for (int p = 0; p < 4; ++p)
        load_lds16(ga + (size_t)p * 32 * GK, As0 + p * 2048 + loff);
    #pragma unroll
    for (int p = 0; p < 2; ++p)
        load_lds16(gb + (size_t)p * 32 * GK, Bs0 + p * 2048 + loff);
    __syncthreads();

    // swizzled read chunks for kk=0,1 (row&7 == col&7 for all fragment rows)
    const int c7  = col & 7;
    const int rq0 = (quad ^ c7) * 8;
    const int rq1 = ((4 + quad) ^ c7) * 8;

    for (int k0 = 0; k0 < GK; k0 += 64) {
        const int cur = (k0 >> 6) & 1;
        ushort* Ac = cur ? As1 : As0;
        ushort* Bc = cur ? Bs1 : Bs0;
        ushort* An = cur ? As0 : As1;
        ushort* Bn = cur ? Bs0 : Bs1;

        if (k0 + 64 < GK) {   // issue prefetch BEFORE compute
            #pragma unroll
            for (int p = 0; p < 4; ++p)
                load_lds16(ga + (k0 + 64) + (size_t)p * 32 * GK, An + p * 2048 + loff);
            #pragma unroll
            for (int p = 0; p < 2; ++p)
                load_lds16(gb + (k0 + 64) + (size_t)p * 32 * GK, Bn + p * 2048 + loff);
        }

        short8 af[4][2], bf[2][2];
        #pragma unroll
        for (int i = 0; i < 4; ++i) {
            const int r = (wm * 64 + i * 16 + col) * 64;
            af[i][0] = *(const short8*)&Ac[r + rq0];
            af[i][1] = *(const short8*)&Ac[r + rq1];
        }
        #pragma unroll
        for (int j = 0; j < 2; ++j) {
            const int r = (wn * 32 + j * 16 + col) * 64;
            bf[j][0] = *(const short8*)&Bc[r + rq0];
            bf[j][1] = *(const short8*)&Bc[r + rq1];
        }
        #pragma unroll
        for (int i = 0; i < 4; ++i)
            #pragma unroll
            for (int j = 0; j < 2; ++j) {
                acc[i][j] = __builtin_amdgcn_mfma_f32_16x16x32_bf16(af[i][0], bf[j][0], acc[i][j], 0, 0, 0);
                acc[i][j] = __builtin_amdgcn_mfma_f32_16x16x32_bf16(af[i][1], bf[j][1], acc[i][j], 0, 0, 0);
            }

        __syncthreads();   // prefetch landed (covered by MFMAs + other block);
                           // fences cur-buffer reuse two iters later
    }
}

// GEMM1: qkv projection; fused split/cast; V emitted transposed. (128x128)
// r13 lesson: do NOT pack V stores — wider live range costs VGPR 84->100 and
// occupancy 24->15% (-8.5us). Occupancy is the binding resource here.
__global__ __launch_bounds__(256) void gemm_qkv_mfma(
    const ushort* __restrict__ A, const ushort* __restrict__ Bt,
    const float* __restrict__ bias,
    ushort* __restrict__ Qb, ushort* __restrict__ Kb, ushort* __restrict__ Vt)
{
    __shared__ __align__(16) ushort As[2][128 * 32];
    __shared__ __align__(16) ushort Bs[2][128 * 32];
    const int n0 = blockIdx.x * 128;
    const int m0 = blockIdx.y * 128;

    floatx4 acc[4][4];
    gemm_core(A, Bt, m0, n0, As[0], As[1], Bs[0], Bs[1], acc);

    const int lane = threadIdx.x & 63;
    const int w    = threadIdx.x >> 6;
    const int col  = lane & 15, quad = lane >> 4;
    const int wm   = w >> 1, wn = w & 1;

    #pragma unroll
    for (int j = 0; j < 4; ++j) {
        const int n = n0 + wn * 64 + j * 16 + col;
        const float bj = bias[n];
        const int part = n >> 10;
        const int h = (n >> 6) & 15;
        const int d = n & 63;
        #pragma unroll
        for (int i = 0; i < 4; ++i)
            #pragma unroll
            for (int r = 0; r < 4; ++r) {
                const int m = m0 + wm * 64 + i * 16 + quad * 4 + r;
                const int b = m >> 11, s = m & 2047;
                const int bh = b * 16 + h;
                const ushort bv = f2bf(acc[i][j][r] + bj);
                if (part == 0)      Qb[((size_t)bh * SEQ + s) * 64 + d] = bv;
                else if (part == 1) Kb[((size_t)bh * SEQ + s) * 64 + d] = bv;
                else                Vt[((size_t)bh * 64 + d) * SEQ + s] = bv;
            }
    }
}

// GEMM2: out = attn_b @ W_out + b_out -> fp32 (128x64 core, BK=64, 2/CU)
__global__ __launch_bounds__(256) void gemm_out_mfma(
    const ushort* __restrict__ A, const ushort* __restrict__ Bt,
    const float* __restrict__ bias, float* __restrict__ out)
{
    __shared__ __align__(16) ushort As[2][128 * 64];   // 32 KB
    __shared__ __align__(16) ushort Bs[2][64 * 64];    // 16 KB
    const int n0 = blockIdx.x * 64;
    const int m0 = blockIdx.y * 128;

    floatx4 acc[4][2];
    gemm_core64(A, Bt, m0, n0, As[0], As[1], Bs[0], Bs[1], acc);

    const int lane = threadIdx.x & 63;
    const int w    = threadIdx.x >> 6;
    const int col  = lane & 15, quad = lane >> 4;
    const int wm   = w >> 1, wn = w & 1;

    #pragma unroll
    for (int j = 0; j < 2; ++j) {
        const int n = n0 + wn * 32 + j * 16 + col;
        const float bj = bias[n];
        #pragma unroll
        for (int i = 0; i < 4; ++i)
            #pragma unroll
            for (int r = 0; r < 4; ++r) {
                const int m = m0 + wm * 64 + i * 16 + quad * 4 + r;
                out[(size_t)m * EMBED_DIM + n] = acc[i][j][r] + bj;
            }
    }
}

// ---------------------------------------------------------------------------
// Flash attention — r7 configuration, best measured (~47us).
// r8 (no staging) = 2.8x worse; r9 (pairing) worse; r10 (setprio) worse.
// ---------------------------------------------------------------------------
#define LP 72

__global__ __launch_bounds__(256) void attn_fused(
    const ushort* __restrict__ Qb, const ushort* __restrict__ Kb,
    const ushort* __restrict__ Vt, ushort* __restrict__ out)
{
    const int id = blockIdx.x;
    const int qt = 31 - (id >> 5);          // reversed: long blocks first (LPT)
    const int bh = id & 31;
    const int b  = bh >> 4, h = bh & 15;
    const int q0 = qt * 64;

    __shared__ __align__(16) ushort Qs[8 * 512];        // 8 KB fragment order
    __shared__ __align__(16) ushort Ks[2][8 * 512];     // 16 KB dbuf
    __shared__ __align__(16) ushort Vs[2][8 * 512];     // 16 KB dbuf
    __shared__ __align__(16) ushort Ps[64 * LP];        // 9 KB
    __shared__ __align__(16) float  ls[4][16];

    const int tid  = threadIdx.x;
    const int w    = tid >> 6;
    const int lane = tid & 63;
    const int col  = lane & 15;
    const int quad = lane >> 4;

    // per-lane global staging pointers (fragment-order gather)
    const ushort* kg[2];
    const ushort* vg[2];
    #pragma unroll
    for (int t = 0; t < 2; ++t) {
        kg[t] = Kb + (size_t)bh * SEQ * 64 + (size_t)(w * 16 + col) * 64 + t * 32 + quad * 8;
        vg[t] = Vt + (size_t)bh * 64 * SEQ + (size_t)(w * 16 + col) * SEQ + t * 32 + quad * 8;
    }

    // prologue: stage Q + K/V tile 0 into buffer 0
    {
        const ushort* Qg = Qb + ((size_t)bh * SEQ + q0) * 64;
        #pragma unroll
        for (int t = 0; t < 2; ++t) {
            load_lds16(Qg + (size_t)(w * 16 + col) * 64 + t * 32 + quad * 8,
                       &Qs[(w * 2 + t) * 512]);
            load_lds16(kg[t], &Ks[0][(w * 2 + t) * 512]);
            load_lds16(vg[t], &Vs[0][(w * 2 + t) * 512]);
            kg[t] += 64 * 64;   // -> tile 1
            vg[t] += 64;
        }
    }
    __syncthreads();

    const short8 a0 = *(const short8*)&Qs[(w * 2 + 0) * 512 + lane * 8];
    const short8 a1 = *(const short8*)&Qs[(w * 2 + 1) * 512 + lane * 8];

    floatx4 acc_o[4];
    #pragma unroll
    for (int dbi = 0; dbi < 4; ++dbi) acc_o[dbi] = (floatx4){0.f, 0.f, 0.f, 0.f};
    float l_lane = 0.f;
    const int myq = w * 16 + col;           // tile-local query owned in S^T

    for (int kt = 0; kt <= qt; ++kt) {
        const int cur = kt & 1;
        const ushort* Kc = Ks[cur];
        const ushort* Vc = Vs[cur];

        if (kt < qt) {   // issue-early prefetch of next tile into other buffer
            ushort* Kn = (ushort*)Ks[cur ^ 1];
            ushort* Vn = (ushort*)Vs[cur ^ 1];
            #pragma unroll
            for (int t = 0; t < 2; ++t) {
                load_lds16(kg[t], &Kn[(w * 2 + t) * 512]);
                load_lds16(vg[t], &Vn[(w * 2 + t) * 512]);
                kg[t] += 64 * 64;
                vg[t] += 64;
            }
        }

        // ---- S^T = K Q^T ----
        floatx4 s_acc[4];
        #pragma unroll
        for (int kb = 0; kb < 4; ++kb) {
            short8 k0f = *(const short8*)&Kc[(kb * 2 + 0) * 512 + lane * 8];
            short8 k1f = *(const short8*)&Kc[(kb * 2 + 1) * 512 + lane * 8];
            floatx4 z = (floatx4){0.f, 0.f, 0.f, 0.f};
            z = __builtin_amdgcn_mfma_f32_16x16x32_bf16(k0f, a0, z, 0, 0, 0);
            z = __builtin_amdgcn_mfma_f32_16x16x32_bf16(k1f, a1, z, 0, 0, 0);
            s_acc[kb] = z;   // lane: query col; regs: keys kb*16+quad*4+r
        }

        // ---- p = exp(s/8); write P rows (ds_write_b64 each) ----
        if (kt == qt) {
            #pragma unroll
            for (int kb = 0; kb < 4; ++kb) {
                const int kbase = kb * 16 + quad * 4;
                float p[4];
                #pragma unroll
                for (int r = 0; r < 4; ++r) {
                    float e = __expf(s_acc[kb][r] * 0.125f);
                    p[r] = (kbase + r > myq) ? 0.f : e;
                    l_lane += p[r];
                }
                uint2 u = { bfpack2(p[0], p[1]), bfpack2(p[2], p[3]) };
                *(uint2*)&Ps[myq * LP + kbase] = u;
            }
        } else {
            #pragma unroll
            for (int kb = 0; kb < 4; ++kb) {
                const int kbase = kb * 16 + quad * 4;
                float p[4];
                #pragma unroll
                for (int r = 0; r < 4; ++r) {
                    p[r] = __expf(s_acc[kb][r] * 0.125f);
                    l_lane += p[r];
                }
                uint2 u = { bfpack2(p[0], p[1]), bfpack2(p[2], p[3]) };
                *(uint2*)&Ps[myq * LP + kbase] = u;
            }
        }

        // ---- O += P V  (Ps rows wave-private) ----
        short8 pa0 = *(const short8*)&Ps[(w * 16 + col) * LP + quad * 8];
        short8 pa1 = *(const short8*)&Ps[(w * 16 + col) * LP + 32 + quad * 8];
        #pragma unroll
        for (int dbi = 0; dbi < 4; ++dbi) {
            short8 vb0 = *(const short8*)&Vc[(dbi * 2 + 0) * 512 + lane * 8];
            short8 vb1 = *(const short8*)&Vc[(dbi * 2 + 1) * 512 + lane * 8];
            acc_o[dbi] = __builtin_amdgcn_mfma_f32_16x16x32_bf16(pa0, vb0, acc_o[dbi], 0, 0, 0);
            acc_o[dbi] = __builtin_amdgcn_mfma_f32_16x16x32_bf16(pa1, vb1, acc_o[dbi], 0, 0, 0);
        }

        __syncthreads();   // prefetch landed (covered by compute above);
                           // fences cur-buffer overwrite two iters later
    }

    // ---- finalize l ----
    l_lane += __shfl_xor(l_lane, 16);
    l_lane += __shfl_xor(l_lane, 32);
    if (quad == 0) ls[w][col] = 1.f / l_lane;   // wave-private
    float4 invv = *(const float4*)&ls[w][quad * 4];

    #pragma unroll
    for (int dbi = 0; dbi < 4; ++dbi)
        #pragma unroll
        for (int r = 0; r < 4; ++r) {
            int q = q0 + w * 16 + quad * 4 + r;
            int d = dbi * 16 + col;
            float inv = (r == 0) ? invv.x : (r == 1) ? invv.y : (r == 2) ? invv.z : invv.w;
            out[((size_t)(b * SEQ + q)) * EMBED_DIM + h * 64 + d] = f2bf(acc_o[dbi][r] * inv);
        }
}

// ---------------------------------------------------------------------------
extern "C" void kernel_launch(void* const* d_in, const int* in_sizes, int n_in,
                              void* d_out, int out_size, void* d_ws, size_t ws_size,
                              hipStream_t stream)
{
    const float* x     = (const float*)d_in[0];
    const float* W_qkv = (const float*)d_in[1];
    const float* b_qkv = (const float*)d_in[2];
    const float* W_out = (const float*)d_in[3];
    const float* b_out = (const float*)d_in[4];
    float* out = (float*)d_out;

    const int M  = BATCH * SEQ;            // 4096
    const int D  = EMBED_DIM;              // 1024
    const int N1 = 3 * D;                  // 3072
    const size_t HE = (size_t)BATCH * NUM_HEADS * SEQ * 64;  // 4M

    ushort* xb    = (ushort*)d_ws;
    ushort* Wqb_t = xb + (size_t)M * D;
    ushort* Wob_t = Wqb_t + (size_t)D * N1;
    ushort* Qb    = Wob_t + (size_t)D * D;
    ushort* Kb    = Qb + HE;
    ushort* Vt    = Kb + HE;
    ushort* attnb = Vt + HE;

    // 0) fused prep: cast x, transpose+cast weights
    prep_all<<<5120, 256, 0, stream>>>(x, W_qkv, W_out, xb, Wqb_t, Wob_t);

    // 1) qkv projection — 128x128 (round-0 best), 768 blocks = 3/CU
    gemm_qkv_mfma<<<dim3(N1 / 128, M / 128), 256, 0, stream>>>(
        xb, Wqb_t, b_qkv, Qb, Kb, Vt);

    // 2) flash attention — staged v1 (r7 best), 1024 blocks = 3/CU
    attn_fused<<<dim3(32 * 32), 256, 0, stream>>>(Qb, Kb, Vt, attnb);

    // 3) output projection — 128x64, BK=64 (16 K-steps), 512 blocks = 2/CU
    gemm_out_mfma<<<dim3(D / 64, M / 128), 256, 0, stream>>>(
        attnb, Wob_t, b_out, out);
}